// Round 21
// baseline (2919.135 us; speedup 1.0000x reference)
//
#include <hip/hip_runtime.h>
#include <hip/hip_fp16.h>

typedef _Float16 f16;
typedef _Float16 half8 __attribute__((ext_vector_type(8)));
typedef float f32x4 __attribute__((ext_vector_type(4)));
typedef unsigned int u32;
typedef unsigned long long u64;
typedef unsigned short u16;

// Recurrent kernel config (round-4 verified geometry)
#define WCOLS 96
#define WROWB 1040
#define LDS_W (WCOLS * WROWB)       // 99840 (dead space: occupancy guard, 1 blk/CU)
#define LDS_A (16 * WROWB)          // 16640
#define LDS_H (16 * 33 * 4)         // 2112
#define LDS_REC (LDS_W + LDS_A + LDS_H + 32)

// ---- MALL primitives (round-10 proven) ----
#define A_ADD32(p, v)  __hip_atomic_fetch_add((u32*)(p), (u32)(v), __ATOMIC_RELAXED, __HIP_MEMORY_SCOPE_AGENT)
#define SYS_LD32(p)    __hip_atomic_load((const u32*)(p), __ATOMIC_RELAXED, __HIP_MEMORY_SCOPE_SYSTEM)
#define SYS_LD64(p)    __hip_atomic_load((const u64*)(p), __ATOMIC_RELAXED, __HIP_MEMORY_SCOPE_SYSTEM)
#define SYS_ST32(p, v) __hip_atomic_store((u32*)(p), (u32)(v), __ATOMIC_RELAXED, __HIP_MEMORY_SCOPE_SYSTEM)
#define SYS_ST64(p, v) __hip_atomic_store((u64*)(p), (u64)(v), __ATOMIC_RELAXED, __HIP_MEMORY_SCOPE_SYSTEM)

// ---- XCD-local TCC primitives (r12/r15/r16/r19/r20 proven) ----
static __device__ __forceinline__ void tcc_swap32(u32* p, u32 v) {
  asm volatile("global_atomic_swap %0, %1, off" :: "v"(p), "v"(v) : "memory");
}
static __device__ __forceinline__ void tcc_swap64(u64* p, u64 v) {
  asm volatile("global_atomic_swap_x2 %0, %1, off" :: "v"(p), "v"(v) : "memory");
}
static __device__ __forceinline__ u32 tcc_add_ret0(u32* p) {
  u32 ret;
  asm volatile("global_atomic_add %0, %1, %2, off sc0\n\ts_waitcnt vmcnt(0)"
               : "=&v"(ret) : "v"(p), "v"(0u) : "memory");
  return ret;
}
// sc1 load: L1-bypass, served concurrently by this XCD's L2.
static __device__ __forceinline__ u32 sc1_ld32(const u32* p) {
  u32 r;
  asm volatile("global_load_dword %0, %1, off sc1\n\ts_waitcnt vmcnt(0)"
               : "=v"(r) : "v"(p) : "memory");
  return r;
}
// MALL-direct (sc0 sc1) issue-only u16 load (r16-proven pre pipeline).
static __device__ __forceinline__ void sysld_u16_issue(u32& dst, const void* p) {
  asm volatile("global_load_ushort %0, %1, off sc0 sc1"
               : "=v"(dst) : "v"(p) : "memory");
}

// syncb layout (dwords): [0..7] probe hist, [8..15] per-XCD claim, [16] global
// claim, [24] global abort; main cnt 64+g*32; test cnt 256+g*32; verdicts
// 512+g*512+cb*32; L2 slots 4096+g*512+cb*32; test slots 6144+g*512+cb*32.

// ---------------- probe: per-XCD dispatch histogram ------------------------
__global__ void probe_xcd_k(u32* syncb) {
  if (threadIdx.x == 0) {
    u32 xcc;
    asm volatile("s_getreg_b32 %0, hwreg(HW_REG_XCC_ID)" : "=s"(xcc));
    __hip_atomic_fetch_add(syncb + (xcc & 7u), 1u, __ATOMIC_RELAXED,
                           __HIP_MEMORY_SCOPE_AGENT);
  }
}

// ---------------- weight convert: W^T f16 [1536 cols][1024 k] -------------
__global__ void cvt_weights_k(const float* __restrict__ wr, const float* __restrict__ wz,
                              const float* __restrict__ wh, f16* __restrict__ WT) {
  int k = blockIdx.x;
  int gate = blockIdx.y;
  int c = threadIdx.x;
  const float* w = (gate == 0) ? wr : (gate == 1) ? wz : wh;
  WT[((size_t)(gate * 512 + c)) * 1024 + k] = (f16)w[(size_t)k * 512 + c];
}

// ---------------- precompute pre[t][b][1536] = x_t @ Wx + bias (f16) ------
__global__ __launch_bounds__(256) void precompute_x_k(
    const float* __restrict__ x, const f16* __restrict__ WT,
    const float* __restrict__ br, const float* __restrict__ bz,
    const float* __restrict__ bh, f16* __restrict__ pre) {
  __shared__ char As[64 * 80];
  __shared__ char Bs[256 * 80];
  const int m0 = blockIdx.x * 64;
  const int n0 = blockIdx.y * 256;
  const int tid = threadIdx.x;
  const int lane = tid & 63;
  const int w = tid >> 6;
  f32x4 acc[16];
#pragma unroll
  for (int i = 0; i < 16; ++i) acc[i] = (f32x4){0.f, 0.f, 0.f, 0.f};

  for (int kk = 0; kk < 16; ++kk) {
    {
      int row = tid >> 2, kc = (tid & 3) * 8;
      const float* s = x + (size_t)(m0 + row) * 512 + kk * 32 + kc;
      float4 v0 = ((const float4*)s)[0];
      float4 v1 = ((const float4*)s)[1];
      half8 h;
      h[0] = (f16)v0.x; h[1] = (f16)v0.y; h[2] = (f16)v0.z; h[3] = (f16)v0.w;
      h[4] = (f16)v1.x; h[5] = (f16)v1.y; h[6] = (f16)v1.z; h[7] = (f16)v1.w;
      *(half8*)(As + row * 80 + kc * 2) = h;
      const uint4* bsrc = (const uint4*)(WT + ((size_t)(n0 + tid)) * 1024 + 512 + kk * 32);
      uint4* bdst = (uint4*)(Bs + tid * 80);
      bdst[0] = bsrc[0]; bdst[1] = bsrc[1]; bdst[2] = bsrc[2]; bdst[3] = bsrc[3];
    }
    __syncthreads();
    half8 a = *(const half8*)(As + (w * 16 + (lane & 15)) * 80 + (lane >> 4) * 16);
#pragma unroll
    for (int nt = 0; nt < 16; ++nt) {
      half8 b = *(const half8*)(Bs + (nt * 16 + (lane & 15)) * 80 + (lane >> 4) * 16);
      acc[nt] = __builtin_amdgcn_mfma_f32_16x16x32_f16(a, b, acc[nt], 0, 0, 0);
    }
    __syncthreads();
  }
#pragma unroll
  for (int nt = 0; nt < 16; ++nt) {
    int col = n0 + nt * 16 + (lane & 15);
    int gate = col >> 9, ci = col & 511;
    float bias = ((gate == 0) ? br : (gate == 1) ? bz : bh)[ci];
#pragma unroll
    for (int r = 0; r < 4; ++r) {
      int m = m0 + w * 16 + (lane >> 4) * 4 + r;
      int b = m >> 9, t = m & 511;
      pre[((size_t)t * 64 + b) * 1536 + col] = (f16)(acc[nt][r] + bias);
    }
  }
}

// ---------------- persistent recurrent kernel -----------------------------
__global__ __launch_bounds__(256, 1) void gru_rec_k(
    const f16* __restrict__ WT, const f16* __restrict__ pre,
    const float* __restrict__ h0, f16* h16, f16* hr16,
    u32* syncb, float* __restrict__ out) {
  extern __shared__ char smem[];
  char* Al = smem + LDS_W;
  float* Hl = (float*)(smem + LDS_W + LDS_A);
  volatile int* s_misc = (int*)(smem + LDS_W + LDS_A + LDS_H);
  const int tid = threadIdx.x;
  const int lane = tid & 63;
  const int w = tid >> 6;

  // ---- roster (r12-proven) ----
  if (tid == 0) {
    u32 xcc;
    asm volatile("s_getreg_b32 %0, hwreg(HW_REG_XCC_ID)" : "=s"(xcc));
    xcc &= 7u;
    int trusted = 1;
    for (int i = 0; i < 8; ++i)
      if (SYS_LD32(syncb + i) < 16u) trusted = 0;
    int g = 0, cb = 0, mode = 0;
    if (trusted) {
      u32 slot = A_ADD32(syncb + 8 + xcc, 1u);
      if (xcc < 4u && slot < 16u) { g = (int)xcc; cb = (int)slot; mode = 2; }
    } else {
      u32 slot = A_ADD32(syncb + 16, 1u);
      if (slot < 64u) { g = (int)(slot & 3u); cb = (int)(slot >> 2); mode = 1; }
    }
    s_misc[0] = g; s_misc[1] = cb; s_misc[2] = mode;
    s_misc[3] = 0; s_misc[4] = 1; s_misc[5] = 0;
  }
  __syncthreads();
  const int mode = s_misc[2];
  if (mode == 0) return;
  const int g = s_misc[0];
  const int cb = s_misc[1];

  u32* cnt     = syncb + 64 + g * 32;
  u32* tcnt    = syncb + 256 + g * 32;
  u32* verds   = syncb + 512 + g * 512;
  u32* l2slots = syncb + 4096 + g * 512;
  u32* tsts    = syncb + 6144 + g * 512;
  u32* abortf  = syncb + 24;

  // ---- MALL barrier (r10-proven, full drain) ----
  auto gbar = [&](u32* c, u32 target) -> int {
    __syncthreads();
    if (tid == 0) {
      A_ADD32(c, 1u);
      u32 it = 0;
      while (SYS_LD32(c) < 16u * target) {
        __builtin_amdgcn_s_sleep(1);
        if (((++it) & 63u) == 0u) {
          if (SYS_LD32(abortf) != 0u) { s_misc[3] = 1; break; }
          if (it > 400000u) { A_ADD32(abortf, 1u); s_misc[3] = 1; break; }
        }
      }
    }
    __syncthreads();
    return s_misc[3];
  };

  // ---- self-test: TCC-swap produce -> sc1-load consume, twice (r15) ----
  int l2m = 0, ab = 0;
  if (mode == 2) {
    u32* mytst = tsts + cb * 32;
    if (tid == 0) tcc_swap32(mytst, 0xA5000000u | (u32)cb);
    ab = gbar(tcnt, 1u);
    if (!ab) {
      if (tid < 16) {
        u32 v = sc1_ld32(tsts + tid * 32);
        if (v != (0xA5000000u | (u32)tid)) s_misc[4] = 0;
      }
      __syncthreads();
      if (tid == 0) tcc_swap32(mytst, 0x5A000000u | (u32)cb);
      ab = gbar(tcnt, 2u);
    }
    if (!ab) {
      if (tid < 16) {
        u32 v = sc1_ld32(tsts + tid * 32);       // stale-L1 detector
        if (v != (0x5A000000u | (u32)tid)) s_misc[4] = 0;
        u32 v2 = tcc_add_ret0(tsts + tid * 32);  // RMW cross-check
        if (v2 != (0x5A000000u | (u32)tid)) s_misc[4] = 0;
      }
      __syncthreads();
      if (tid == 0) SYS_ST32(verds + cb * 32, 1u + (u32)s_misc[4]);
      ab = gbar(tcnt, 3u);
      if (tid == 0) s_misc[5] = 1;
      __syncthreads();
      if (tid < 16) {
        if (SYS_LD32(verds + tid * 32) != 2u) s_misc[5] = 0;
      }
      __syncthreads();
      l2m = s_misc[5];
    }
  }

  // ---- MALL-mode staging (r10-proven) ----
  auto stage_mall = [&](const f16* src16) {
    const u64* s = (const u64*)src16;
    u64 tmp[8];
#pragma unroll
    for (int i = 0; i < 8; ++i) tmp[i] = SYS_LD64(s + i * 256 + tid);
#pragma unroll
    for (int i = 0; i < 8; ++i) {
      int u = i * 256 + tid;
      *(u64*)(Al + (u >> 7) * WROWB + (u & 127) * 8) = tmp[i];
    }
    asm volatile("s_waitcnt vmcnt(0)" ::: "memory");
    __syncthreads();
    __builtin_amdgcn_sched_barrier(0);
  };

  // ---- FUSED barrier+stage (L2 mode). Per phase:
  //   waitcnt (vmcnt(8) keeps pre loads in flight) -> s_barrier (Al/Hl
  //   read/write separation) -> tid0 swap-arrive -> EACH WAVE polls the 16
  //   slots with its lanes (sc1, concurrent) and, on success, immediately
  //   issues its own staged loads -> __syncthreads publishes Al.
  //   No release barrier, no serial poll->stage hop. ----
  auto barstage = [&](u32 target, bool keep, const f16* src16) -> int {
    if (!l2m) {
      int a = gbar(cnt, target);
      if (!a) stage_mall(src16);
      return a ? a : s_misc[3];
    }
    if (keep) asm volatile("s_waitcnt vmcnt(8) lgkmcnt(0)" ::: "memory");
    else      asm volatile("s_waitcnt vmcnt(0) lgkmcnt(0)" ::: "memory");
    __builtin_amdgcn_sched_barrier(0);
    __builtin_amdgcn_s_barrier();
    if (tid == 0) tcc_swap32(l2slots + cb * 32, target);
    {
      u32* pl = l2slots + (lane & 15) * 32;
      u32 it = 0;
      for (;;) {
        bool ok = (sc1_ld32(pl) >= target);
        if (__all(ok)) break;
        if (((++it) & 63u) == 0u) {
          if (SYS_LD32(abortf) != 0u) { if (lane == 0) s_misc[3] = 1; break; }
          if (it > 200000u) { SYS_ST32(abortf, 1u); if (lane == 0) s_misc[3] = 1; break; }
        }
      }
    }
    {  // fused stage: this wave's producers are all done -> load now
      const char* s = (const char*)src16;
      uint4 t0, t1, t2, t3;
      asm volatile(
          "global_load_dwordx4 %0, %4, off sc1\n\t"
          "global_load_dwordx4 %1, %5, off sc1\n\t"
          "global_load_dwordx4 %2, %6, off sc1\n\t"
          "global_load_dwordx4 %3, %7, off sc1\n\t"
          "s_waitcnt vmcnt(0)"
          : "=&v"(t0), "=&v"(t1), "=&v"(t2), "=&v"(t3)
          : "v"(s + (size_t)tid * 16), "v"(s + (size_t)(256 + tid) * 16),
            "v"(s + (size_t)(512 + tid) * 16), "v"(s + (size_t)(768 + tid) * 16)
          : "memory");
      { int u = tid;       *(uint4*)(Al + (u >> 6) * WROWB + (u & 63) * 16) = t0; }
      { int u = 256 + tid; *(uint4*)(Al + (u >> 6) * WROWB + (u & 63) * 16) = t1; }
      { int u = 512 + tid; *(uint4*)(Al + (u >> 6) * WROWB + (u & 63) * 16) = t2; }
      { int u = 768 + tid; *(uint4*)(Al + (u >> 6) * WROWB + (u & 63) * 16) = t3; }
    }
    __syncthreads();
    __builtin_amdgcn_sched_barrier(0);
    return s_misc[3];
  };

  // ---- block-private fp32 h slice -> LDS ----
  for (int i = tid; i < 16 * 32; i += 256) {
    int row = i >> 5, c = i & 31;
    Hl[row * 33 + c] = h0[(size_t)(g * 16 + row) * 512 + cb * 32 + c];
  }
  // ---- h16 init (one writer per group) ----
  if (cb == 0) {
    u64* dst = (u64*)(h16 + (size_t)g * 16 * 512);
    for (int i = tid; i < 2048; i += 256) {
      int e0 = i * 4;
      const float* hp = h0 + (size_t)(g * 16 + (e0 >> 9)) * 512 + (e0 & 511);
      u16 b0 = __builtin_bit_cast(u16, (f16)hp[0]);
      u16 b1 = __builtin_bit_cast(u16, (f16)hp[1]);
      u16 b2 = __builtin_bit_cast(u16, (f16)hp[2]);
      u16 b3 = __builtin_bit_cast(u16, (f16)hp[3]);
      u64 v = (u64)b0 | ((u64)b1 << 16) | ((u64)b2 << 32) | ((u64)b3 << 48);
      if (l2m) tcc_swap64(dst + i, v); else SYS_ST64(dst + i, v);
    }
  }

  // ---- per-thread constant indices ----
  const int rq = lane >> 4;
  const int lc1 = w * 16 + (lane & 15);
  const int ci1 = cb * 32 + (lc1 & 31);
  const int gcol1 = (lc1 < 32) ? ci1 : (512 + ci1);
  const int lch = (w >= 2) ? ((w - 2) * 16 + (lane & 15)) : 0;
  const int ci2 = cb * 32 + lch;
  const char* Ab  = Al + (lane & 15) * WROWB + rq * 16;
  const int gcol2 = (w >= 2) ? (1024 + ci2) : gcol1;

  // ---- B-fragments (weights) -> REGISTERS (r20-proven mapping) ----
  half8 breg1[16], breg2[16];
  {
    const int gate1col = ((lc1 < 32) ? 0 : 512) + ci1;
    const uint4* c1 = (const uint4*)(WT + (size_t)gate1col * 1024);
    const uint4* c2 = (const uint4*)(WT + (size_t)(1024 + ci2) * 1024);
#pragma unroll
    for (int kk = 0; kk < 16; ++kk) {
      breg1[kk] = __builtin_bit_cast(half8, c1[rq + kk * 4]);
      breg2[kk] = __builtin_bit_cast(half8, c2[rq + kk * 4]);
    }
  }

  // ---- pre[] pipeline (r16-proven): MALL-direct issue, convert post-drain --
  u32 q1[4], q2[4];
  float p1r[4], p2r[4];
  auto issue_pre = [&](int t) {
#pragma unroll
    for (int r = 0; r < 4; ++r) {
      const int grow = g * 16 + rq * 4 + r;
      const u16* base = (const u16*)pre + ((size_t)t * 64 + grow) * 1536;
      sysld_u16_issue(q1[r], base + gcol1);
      sysld_u16_issue(q2[r], base + gcol2);
    }
  };
  auto convert_pre = [&]() {
#pragma unroll
    for (int r = 0; r < 4; ++r) {
      p1r[r] = (float)__builtin_bit_cast(f16, (u16)(q1[r] & 0xffffu));
      p2r[r] = (float)__builtin_bit_cast(f16, (u16)(q2[r] & 0xffffu));
    }
  };

  // gate write: u64-packed (4 cols), mode-appropriate primitive
  auto gwrite = [&](f16* base, int grow, int ci, u32 hb_u32) {
    u32 p01 = hb_u32 | (((u32)(u16)__shfl_xor((int)hb_u32, 1, 64)) << 16);
    u64 q = (u64)p01 | (((u64)(u32)__shfl_xor((int)p01, 2, 64)) << 32);
    if (!(lane & 3)) {
      u64* dst = (u64*)(base + (size_t)grow * 512 + ci);
      if (l2m) tcc_swap64(dst, q); else SYS_ST64(dst, q);
    }
  };

  f16* const h16g  = h16 + (size_t)g * 16 * 512;
  f16* const hr16g = hr16 + (size_t)g * 16 * 512;

  issue_pre(0);
  ab = ab ? ab : barstage(1u, false, h16g);   // arrive + stage h_0

  f32x4 zreg = {0.f, 0.f, 0.f, 0.f};
  for (int t = 0; t < 512 && !ab; ++t) {
    convert_pre();
    // ---- phase 1: r,z = hard_sigmoid(h @ [Wr|Wz] + pre) (Al = h_t) ----
    f32x4 acc = {0.f, 0.f, 0.f, 0.f};
#pragma unroll
    for (int kk = 0; kk < 16; ++kk) {
      half8 a = *(const half8*)(Ab + kk * 64);
      acc = __builtin_amdgcn_mfma_f32_16x16x32_f16(a, breg1[kk], acc, 0, 0, 0);
    }
    if (lc1 < 32) {   // waves 0,1: r-gate -> hr16
#pragma unroll
      for (int r = 0; r < 4; ++r) {
        float v = acc[r] + p1r[r];
        float gt = fmaxf(0.f, fminf(1.f, 0.2f * v + 0.5f));
        float hv = Hl[(rq * 4 + r) * 33 + (lc1 & 31)];
        u32 hb = (u32)__builtin_bit_cast(u16, (f16)(hv * gt));
        gwrite(hr16, g * 16 + rq * 4 + r, ci1, hb);
      }
    } else {          // waves 2,3: z-gate -> registers
#pragma unroll
      for (int r = 0; r < 4; ++r) {
        float v = acc[r] + p1r[r];
        zreg[r] = fmaxf(0.f, fminf(1.f, 0.2f * v + 0.5f));
      }
    }
    if (t < 511) issue_pre(t + 1);   // after swaps -> vmcnt(8) keeps in flight
    ab = barstage(2u * t + 2u, t < 511, hr16g);  // arrive + stage hr_t
    if (ab) break;
    // ---- phase 2 (waves 2,3): hhat = tanh(hr @ Wh + pre); blend ----
    if (w >= 2) {
      f32x4 acc2 = {0.f, 0.f, 0.f, 0.f};
#pragma unroll
      for (int kk = 0; kk < 16; ++kk) {
        half8 a = *(const half8*)(Ab + kk * 64);
        acc2 = __builtin_amdgcn_mfma_f32_16x16x32_f16(a, breg2[kk], acc2, 0, 0, 0);
      }
#pragma unroll
      for (int r = 0; r < 4; ++r) {
        float v = acc2[r] + p2r[r];
        float vc = fminf(9.f, fmaxf(-9.f, v));
        float e = __expf(2.f * vc);
        float hh = (e - 1.f) * __builtin_amdgcn_rcpf(e + 1.f);
        const int row = rq * 4 + r;
        float ho = Hl[row * 33 + lch];
        float z = zreg[r];
        float hn = ho * (1.f - z) + z * hh;
        Hl[row * 33 + lch] = hn;
        u32 hb = (u32)__builtin_bit_cast(u16, (f16)hn);
        gwrite(h16, g * 16 + row, ci2, hb);
        if (t == 511) out[(size_t)(g * 16 + row) * 512 + ci2] = hn;
      }
    }
    if (t < 511) ab = barstage(2u * t + 3u, false, h16g);  // arrive + stage h_{t+1}
  }
}

// ---------------- launch ---------------------------------------------------
extern "C" void kernel_launch(void* const* d_in, const int* in_sizes, int n_in,
                              void* d_out, int out_size, void* d_ws, size_t ws_size,
                              hipStream_t stream) {
  const float* x  = (const float*)d_in[0];
  const float* h0 = (const float*)d_in[1];
  const float* wr = (const float*)d_in[2];
  const float* wz = (const float*)d_in[3];
  const float* wh = (const float*)d_in[4];
  const float* br = (const float*)d_in[5];
  const float* bz = (const float*)d_in[6];
  const float* bh = (const float*)d_in[7];
  float* out = (float*)d_out;

  char* ws = (char*)d_ws;
  size_t off = 0;
  f16* WT = (f16*)(ws + off);   off += (size_t)1536 * 1024 * 2;        // 3 MiB
  f16* pre = (f16*)(ws + off);  off += (size_t)512 * 64 * 1536 * 2;    // 96 MiB
  f16* h16 = (f16*)(ws + off);  off += (size_t)64 * 512 * 2;
  f16* hr16 = (f16*)(ws + off); off += (size_t)64 * 512 * 2;
  u32* syncb = (u32*)(ws + off); off += 32768;

  if (ws_size < off) {
    hipMemsetAsync(d_out, 0, (size_t)out_size * 4, stream);
    return;
  }

  hipMemsetAsync(syncb, 0, 32768, stream);
  probe_xcd_k<<<512, 64, 0, stream>>>(syncb);
  cvt_weights_k<<<dim3(1024, 3), 512, 0, stream>>>(wr, wz, wh, WT);
  precompute_x_k<<<dim3(512, 6), 256, 0, stream>>>(x, WT, br, bz, bh, pre);
  hipFuncSetAttribute(reinterpret_cast<const void*>(gru_rec_k),
                      hipFuncAttributeMaxDynamicSharedMemorySize, LDS_REC);
  gru_rec_k<<<1024, 256, LDS_REC, stream>>>(WT, pre, h0, h16, hr16, syncb, out);
}

// Round 22
// 2587.960 us; speedup vs baseline: 1.1280x; 1.1280x over previous
//
#include <hip/hip_runtime.h>
#include <hip/hip_fp16.h>

typedef _Float16 f16;
typedef _Float16 half8 __attribute__((ext_vector_type(8)));
typedef float f32x4 __attribute__((ext_vector_type(4)));
typedef unsigned int u32;
typedef unsigned long long u64;
typedef unsigned short u16;

// Recurrent kernel config (round-4 verified geometry)
#define WCOLS 96           // 3 gates * 32 cols owned per block
#define WROWB 1040         // padded bytes per 512-f16 row
#define LDS_W (WCOLS * WROWB)       // 99840 (dead space: occupancy guard, 1 blk/CU)
#define LDS_A (16 * WROWB)          // 16640
#define LDS_H (16 * 33 * 4)         // 2112
#define LDS_REC (LDS_W + LDS_A + LDS_H + 32)

// ---- MALL primitives (round-10 proven) ----
#define A_ADD32(p, v)  __hip_atomic_fetch_add((u32*)(p), (u32)(v), __ATOMIC_RELAXED, __HIP_MEMORY_SCOPE_AGENT)
#define SYS_LD32(p)    __hip_atomic_load((const u32*)(p), __ATOMIC_RELAXED, __HIP_MEMORY_SCOPE_SYSTEM)
#define SYS_LD64(p)    __hip_atomic_load((const u64*)(p), __ATOMIC_RELAXED, __HIP_MEMORY_SCOPE_SYSTEM)
#define SYS_ST32(p, v) __hip_atomic_store((u32*)(p), (u32)(v), __ATOMIC_RELAXED, __HIP_MEMORY_SCOPE_SYSTEM)
#define SYS_ST64(p, v) __hip_atomic_store((u64*)(p), (u64)(v), __ATOMIC_RELAXED, __HIP_MEMORY_SCOPE_SYSTEM)

// ---- XCD-local TCC primitives (r12/r15/r16/r19/r20 proven in production) ----
static __device__ __forceinline__ void tcc_swap32(u32* p, u32 v) {
  asm volatile("global_atomic_swap %0, %1, off" :: "v"(p), "v"(v) : "memory");
}
static __device__ __forceinline__ void tcc_swap64(u64* p, u64 v) {
  asm volatile("global_atomic_swap_x2 %0, %1, off" :: "v"(p), "v"(v) : "memory");
}
static __device__ __forceinline__ u32 tcc_add_ret0(u32* p) {
  u32 ret;
  asm volatile("global_atomic_add %0, %1, %2, off sc0\n\ts_waitcnt vmcnt(0)"
               : "=&v"(ret) : "v"(p), "v"(0u) : "memory");
  return ret;
}
// sc1 load: L1-bypass, served concurrently by this XCD's L2 (no RMW
// serialization). Freshness for swap->load is what the self-test validates.
static __device__ __forceinline__ u32 sc1_ld32(const u32* p) {
  u32 r;
  asm volatile("global_load_dword %0, %1, off sc1\n\ts_waitcnt vmcnt(0)"
               : "=v"(r) : "v"(p) : "memory");
  return r;
}
// MALL-direct (sc0 sc1) issue-only u16 load (r16-proven pre pipeline).
static __device__ __forceinline__ void sysld_u16_issue(u32& dst, const void* p) {
  asm volatile("global_load_ushort %0, %1, off sc0 sc1"
               : "=v"(dst) : "v"(p) : "memory");
}

// syncb layout (dwords): [0..7] probe hist, [8..15] per-XCD claim, [16] global
// claim, [24] global abort; main cnt 64+g*32; test cnt 256+g*32; verdicts
// 512+g*512+cb*32; L2 slots 4096+g*512+cb*32; test slots 6144+g*512+cb*32.

// ---------------- probe: per-XCD dispatch histogram ------------------------
__global__ void probe_xcd_k(u32* syncb) {
  if (threadIdx.x == 0) {
    u32 xcc;
    asm volatile("s_getreg_b32 %0, hwreg(HW_REG_XCC_ID)" : "=s"(xcc));
    __hip_atomic_fetch_add(syncb + (xcc & 7u), 1u, __ATOMIC_RELAXED,
                           __HIP_MEMORY_SCOPE_AGENT);
  }
}

// ---------------- weight convert: W^T f16 [1536 cols][1024 k] -------------
__global__ void cvt_weights_k(const float* __restrict__ wr, const float* __restrict__ wz,
                              const float* __restrict__ wh, f16* __restrict__ WT) {
  int k = blockIdx.x;
  int gate = blockIdx.y;
  int c = threadIdx.x;
  const float* w = (gate == 0) ? wr : (gate == 1) ? wz : wh;
  WT[((size_t)(gate * 512 + c)) * 1024 + k] = (f16)w[(size_t)k * 512 + c];
}

// ---------------- precompute pre[t][b][1536] = x_t @ Wx + bias (f16) ------
__global__ __launch_bounds__(256) void precompute_x_k(
    const float* __restrict__ x, const f16* __restrict__ WT,
    const float* __restrict__ br, const float* __restrict__ bz,
    const float* __restrict__ bh, f16* __restrict__ pre) {
  __shared__ char As[64 * 80];
  __shared__ char Bs[256 * 80];
  const int m0 = blockIdx.x * 64;
  const int n0 = blockIdx.y * 256;
  const int tid = threadIdx.x;
  const int lane = tid & 63;
  const int w = tid >> 6;
  f32x4 acc[16];
#pragma unroll
  for (int i = 0; i < 16; ++i) acc[i] = (f32x4){0.f, 0.f, 0.f, 0.f};

  for (int kk = 0; kk < 16; ++kk) {
    {
      int row = tid >> 2, kc = (tid & 3) * 8;
      const float* s = x + (size_t)(m0 + row) * 512 + kk * 32 + kc;
      float4 v0 = ((const float4*)s)[0];
      float4 v1 = ((const float4*)s)[1];
      half8 h;
      h[0] = (f16)v0.x; h[1] = (f16)v0.y; h[2] = (f16)v0.z; h[3] = (f16)v0.w;
      h[4] = (f16)v1.x; h[5] = (f16)v1.y; h[6] = (f16)v1.z; h[7] = (f16)v1.w;
      *(half8*)(As + row * 80 + kc * 2) = h;
      const uint4* bsrc = (const uint4*)(WT + ((size_t)(n0 + tid)) * 1024 + 512 + kk * 32);
      uint4* bdst = (uint4*)(Bs + tid * 80);
      bdst[0] = bsrc[0]; bdst[1] = bsrc[1]; bdst[2] = bsrc[2]; bdst[3] = bsrc[3];
    }
    __syncthreads();
    half8 a = *(const half8*)(As + (w * 16 + (lane & 15)) * 80 + (lane >> 4) * 16);
#pragma unroll
    for (int nt = 0; nt < 16; ++nt) {
      half8 b = *(const half8*)(Bs + (nt * 16 + (lane & 15)) * 80 + (lane >> 4) * 16);
      acc[nt] = __builtin_amdgcn_mfma_f32_16x16x32_f16(a, b, acc[nt], 0, 0, 0);
    }
    __syncthreads();
  }
#pragma unroll
  for (int nt = 0; nt < 16; ++nt) {
    int col = n0 + nt * 16 + (lane & 15);
    int gate = col >> 9, ci = col & 511;
    float bias = ((gate == 0) ? br : (gate == 1) ? bz : bh)[ci];
#pragma unroll
    for (int r = 0; r < 4; ++r) {
      int m = m0 + w * 16 + (lane >> 4) * 4 + r;
      int b = m >> 9, t = m & 511;
      pre[((size_t)t * 64 + b) * 1536 + col] = (f16)(acc[nt][r] + bias);
    }
  }
}

// ---------------- persistent recurrent kernel -----------------------------
__global__ __launch_bounds__(256, 1) void gru_rec_k(
    const f16* __restrict__ WT, const f16* __restrict__ pre,
    const float* __restrict__ h0, f16* h16, f16* hr16,
    u32* syncb, float* __restrict__ out) {
  extern __shared__ char smem[];
  char* Al = smem + LDS_W;           // staging (LDS_W region is dead space)
  float* Hl = (float*)(smem + LDS_W + LDS_A);
  volatile int* s_misc = (int*)(smem + LDS_W + LDS_A + LDS_H);
  const int tid = threadIdx.x;
  const int lane = tid & 63;
  const int w = tid >> 6;

  // ---- roster (r12-proven) ----
  if (tid == 0) {
    u32 xcc;
    asm volatile("s_getreg_b32 %0, hwreg(HW_REG_XCC_ID)" : "=s"(xcc));
    xcc &= 7u;
    int trusted = 1;
    for (int i = 0; i < 8; ++i)
      if (SYS_LD32(syncb + i) < 16u) trusted = 0;
    int g = 0, cb = 0, mode = 0;   // 0=exit, 1=MALL worker, 2=L2 candidate
    if (trusted) {
      u32 slot = A_ADD32(syncb + 8 + xcc, 1u);
      if (xcc < 4u && slot < 16u) { g = (int)xcc; cb = (int)slot; mode = 2; }
    } else {
      u32 slot = A_ADD32(syncb + 16, 1u);
      if (slot < 64u) { g = (int)(slot & 3u); cb = (int)(slot >> 2); mode = 1; }
    }
    s_misc[0] = g; s_misc[1] = cb; s_misc[2] = mode;
    s_misc[3] = 0; s_misc[4] = 1; s_misc[5] = 0;
  }
  __syncthreads();
  const int mode = s_misc[2];
  if (mode == 0) return;
  const int g = s_misc[0];
  const int cb = s_misc[1];

  u32* cnt     = syncb + 64 + g * 32;
  u32* tcnt    = syncb + 256 + g * 32;
  u32* verds   = syncb + 512 + g * 512;
  u32* l2slots = syncb + 4096 + g * 512;
  u32* tsts    = syncb + 6144 + g * 512;
  u32* abortf  = syncb + 24;

  // ---- MALL barrier (r10-proven, full drain) ----
  auto gbar = [&](u32* c, u32 target) -> int {
    __syncthreads();
    if (tid == 0) {
      A_ADD32(c, 1u);
      u32 it = 0;
      while (SYS_LD32(c) < 16u * target) {
        __builtin_amdgcn_s_sleep(1);
        if (((++it) & 63u) == 0u) {
          if (SYS_LD32(abortf) != 0u) { s_misc[3] = 1; break; }
          if (it > 400000u) { A_ADD32(abortf, 1u); s_misc[3] = 1; break; }
        }
      }
    }
    __syncthreads();
    return s_misc[3];
  };

  // ---- self-test: TCC-swap produce -> sc1-load consume, twice (r15) ----
  int l2m = 0, ab = 0;
  if (mode == 2) {
    u32* mytst = tsts + cb * 32;
    if (tid == 0) tcc_swap32(mytst, 0xA5000000u | (u32)cb);
    ab = gbar(tcnt, 1u);
    if (!ab) {
      if (tid < 16) {
        u32 v = sc1_ld32(tsts + tid * 32);
        if (v != (0xA5000000u | (u32)tid)) s_misc[4] = 0;
      }
      __syncthreads();
      if (tid == 0) tcc_swap32(mytst, 0x5A000000u | (u32)cb);
      ab = gbar(tcnt, 2u);
    }
    if (!ab) {
      if (tid < 16) {
        u32 v = sc1_ld32(tsts + tid * 32);       // stale-L1 detector
        if (v != (0x5A000000u | (u32)tid)) s_misc[4] = 0;
        u32 v2 = tcc_add_ret0(tsts + tid * 32);  // RMW cross-check
        if (v2 != (0x5A000000u | (u32)tid)) s_misc[4] = 0;
      }
      __syncthreads();
      if (tid == 0) SYS_ST32(verds + cb * 32, 1u + (u32)s_misc[4]);
      ab = gbar(tcnt, 3u);
      if (tid == 0) s_misc[5] = 1;
      __syncthreads();
      if (tid < 16) {
        if (SYS_LD32(verds + tid * 32) != 2u) s_misc[5] = 0;
      }
      __syncthreads();
      l2m = s_misc[5];
    }
  }

  // ---- mode-switched barrier (r19 champion: swap-arrive + sc1-load poll) --
  auto barK = [&](u32 target, bool keep) -> int {
    if (!l2m) return gbar(cnt, target);
    if (keep) asm volatile("s_waitcnt vmcnt(8) lgkmcnt(0)" ::: "memory");
    else      asm volatile("s_waitcnt vmcnt(0) lgkmcnt(0)" ::: "memory");
    __builtin_amdgcn_sched_barrier(0);
    __builtin_amdgcn_s_barrier();
    if (tid == 0) tcc_swap32(l2slots + cb * 32, target);
    if (tid < 64) {
      u32* pl = l2slots + (lane & 15) * 32;
      u32 it = 0;
      for (;;) {
        bool ok = true;
        if (lane < 16) ok = (sc1_ld32(pl) >= target);
        if (__all(ok)) break;
        if (((++it) & 63u) == 0u) {
          if (SYS_LD32(abortf) != 0u) { if (lane == 0) s_misc[3] = 1; break; }
          if (it > 200000u) { SYS_ST32(abortf, 1u); if (lane == 0) s_misc[3] = 1; break; }
        }
      }
    }
    asm volatile("s_waitcnt lgkmcnt(0)" ::: "memory");
    __builtin_amdgcn_s_barrier();
    __builtin_amdgcn_sched_barrier(0);
    return s_misc[3];
  };

  // ---- block-private fp32 h slice -> LDS ----
  for (int i = tid; i < 16 * 32; i += 256) {
    int row = i >> 5, c = i & 31;
    Hl[row * 33 + c] = h0[(size_t)(g * 16 + row) * 512 + cb * 32 + c];
  }
  // ---- h16 init (one writer per group), mode-appropriate primitive ----
  if (cb == 0) {
    u64* dst = (u64*)(h16 + (size_t)g * 16 * 512);
    for (int i = tid; i < 2048; i += 256) {
      int e0 = i * 4;
      const float* hp = h0 + (size_t)(g * 16 + (e0 >> 9)) * 512 + (e0 & 511);
      u16 b0 = __builtin_bit_cast(u16, (f16)hp[0]);
      u16 b1 = __builtin_bit_cast(u16, (f16)hp[1]);
      u16 b2 = __builtin_bit_cast(u16, (f16)hp[2]);
      u16 b3 = __builtin_bit_cast(u16, (f16)hp[3]);
      u64 v = (u64)b0 | ((u64)b1 << 16) | ((u64)b2 << 32) | ((u64)b3 << 48);
      if (l2m) tcc_swap64(dst + i, v); else SYS_ST64(dst + i, v);
    }
  }

  // ---- per-thread constant indices ----
  const int rq = lane >> 4;
  const int lc1 = w * 16 + (lane & 15);
  const int ci1 = cb * 32 + (lc1 & 31);
  const int gcol1 = (lc1 < 32) ? ci1 : (512 + ci1);
  const int lch = (w >= 2) ? ((w - 2) * 16 + (lane & 15)) : 0;
  const int ci2 = cb * 32 + lch;
  const char* Ab  = Al + (lane & 15) * WROWB + rq * 16;
  const int gcol2 = (w >= 2) ? (1024 + ci2) : gcol1;

  // ---- B-fragments (weights) -> REGISTERS: constant across all 512 steps.
  // Replaces 16 ds_read_b128/lane/phase (r20-verified mapping).
  half8 breg1[16], breg2[16];
  {
    const int gate1col = ((lc1 < 32) ? 0 : 512) + ci1;  // r or z column
    const uint4* c1 = (const uint4*)(WT + (size_t)gate1col * 1024);
    const uint4* c2 = (const uint4*)(WT + (size_t)(1024 + ci2) * 1024);
#pragma unroll
    for (int kk = 0; kk < 16; ++kk) {
      breg1[kk] = __builtin_bit_cast(half8, c1[rq + kk * 4]);
      breg2[kk] = __builtin_bit_cast(half8, c2[rq + kk * 4]);
    }
  }

  // ---- pre[] pipeline (r16-proven): MALL-direct issue, convert post-drain --
  u32 q1[4], q2[4];
  float p1r[4], p2r[4];
  auto issue_pre = [&](int t) {
#pragma unroll
    for (int r = 0; r < 4; ++r) {
      const int grow = g * 16 + rq * 4 + r;
      const u16* base = (const u16*)pre + ((size_t)t * 64 + grow) * 1536;
      sysld_u16_issue(q1[r], base + gcol1);
      sysld_u16_issue(q2[r], base + gcol2);
    }
  };
  auto convert_pre = [&]() {
#pragma unroll
    for (int r = 0; r < 4; ++r) {
      p1r[r] = (float)__builtin_bit_cast(f16, (u16)(q1[r] & 0xffffu));
      p2r[r] = (float)__builtin_bit_cast(f16, (u16)(q2[r] & 0xffffu));
    }
  };

  // ---- staging: 16KB group state -> Al (r15/r16 proven both modes) ----
  auto stage = [&](const f16* src16) {
    if (l2m) {
      const char* s = (const char*)src16;
      uint4 t0, t1, t2, t3;
      asm volatile(
          "global_load_dwordx4 %0, %4, off sc1\n\t"
          "global_load_dwordx4 %1, %5, off sc1\n\t"
          "global_load_dwordx4 %2, %6, off sc1\n\t"
          "global_load_dwordx4 %3, %7, off sc1\n\t"
          "s_waitcnt vmcnt(0)"
          : "=&v"(t0), "=&v"(t1), "=&v"(t2), "=&v"(t3)
          : "v"(s + (size_t)tid * 16), "v"(s + (size_t)(256 + tid) * 16),
            "v"(s + (size_t)(512 + tid) * 16), "v"(s + (size_t)(768 + tid) * 16)
          : "memory");
      { int u = tid;       *(uint4*)(Al + (u >> 6) * WROWB + (u & 63) * 16) = t0; }
      { int u = 256 + tid; *(uint4*)(Al + (u >> 6) * WROWB + (u & 63) * 16) = t1; }
      { int u = 512 + tid; *(uint4*)(Al + (u >> 6) * WROWB + (u & 63) * 16) = t2; }
      { int u = 768 + tid; *(uint4*)(Al + (u >> 6) * WROWB + (u & 63) * 16) = t3; }
    } else {
      const u64* s = (const u64*)src16;
      u64 tmp[8];
#pragma unroll
      for (int i = 0; i < 8; ++i) tmp[i] = SYS_LD64(s + i * 256 + tid);
#pragma unroll
      for (int i = 0; i < 8; ++i) {
        int u = i * 256 + tid;
        *(u64*)(Al + (u >> 7) * WROWB + (u & 127) * 8) = tmp[i];
      }
      asm volatile("s_waitcnt vmcnt(0)" ::: "memory");  // drain pre loads too
    }
    __syncthreads();
    __builtin_amdgcn_sched_barrier(0);   // q-reg reads must not hoist above
  };

  // gate write: u64-packed (4 cols), mode-appropriate primitive
  auto gwrite = [&](f16* base, int grow, int ci, u32 hb_u32) {
    u32 p01 = hb_u32 | (((u32)(u16)__shfl_xor((int)hb_u32, 1, 64)) << 16);
    u64 q = (u64)p01 | (((u64)(u32)__shfl_xor((int)p01, 2, 64)) << 32);
    if (!(lane & 3)) {
      u64* dst = (u64*)(base + (size_t)grow * 512 + ci);
      if (l2m) tcc_swap64(dst, q); else SYS_ST64(dst, q);
    }
  };

  issue_pre(0);
  ab = ab ? ab : barK(1u, false);

  f16* const h16g  = h16 + (size_t)g * 16 * 512;
  f16* const hr16g = hr16 + (size_t)g * 16 * 512;

  f32x4 zreg = {0.f, 0.f, 0.f, 0.f};
  for (int t = 0; t < 512 && !ab; ++t) {
    // ---- stage h16 -> Al (drains q; then convert raw bits) ----
    stage(h16g);
    convert_pre();
    // ---- phase 1: r,z = hard_sigmoid(h @ [Wr|Wz] + pre) ----
    f32x4 acc = {0.f, 0.f, 0.f, 0.f};
#pragma unroll
    for (int kk = 0; kk < 16; ++kk) {
      half8 a = *(const half8*)(Ab + kk * 64);
      acc = __builtin_amdgcn_mfma_f32_16x16x32_f16(a, breg1[kk], acc, 0, 0, 0);
    }
    if (lc1 < 32) {   // waves 0,1: r-gate -> hr16
#pragma unroll
      for (int r = 0; r < 4; ++r) {
        float v = acc[r] + p1r[r];
        float gt = fmaxf(0.f, fminf(1.f, 0.2f * v + 0.5f));
        float hv = Hl[(rq * 4 + r) * 33 + (lc1 & 31)];
        u32 hb = (u32)__builtin_bit_cast(u16, (f16)(hv * gt));
        gwrite(hr16, g * 16 + rq * 4 + r, ci1, hb);
      }
    } else {          // waves 2,3: z-gate -> registers
#pragma unroll
      for (int r = 0; r < 4; ++r) {
        float v = acc[r] + p1r[r];
        zreg[r] = fmaxf(0.f, fminf(1.f, 0.2f * v + 0.5f));
      }
    }
    // issue next step's pre loads AFTER the swaps (swaps oldest -> vmcnt(8)
    // drains swaps, keeps these 8 in flight across the barrier)
    if (t < 511) issue_pre(t + 1);
    ab = barK(2u * t + 2u, t < 511);
    if (ab) break;
    // ---- stage hr16 -> Al (vmcnt(0) completes the in-flight pre loads) ----
    stage(hr16g);
    // ---- phase 2 (waves 2,3): hhat = tanh(hr @ Wh + pre); blend ----
    if (w >= 2) {
      f32x4 acc2 = {0.f, 0.f, 0.f, 0.f};
#pragma unroll
      for (int kk = 0; kk < 16; ++kk) {
        half8 a = *(const half8*)(Ab + kk * 64);
        acc2 = __builtin_amdgcn_mfma_f32_16x16x32_f16(a, breg2[kk], acc2, 0, 0, 0);
      }
#pragma unroll
      for (int r = 0; r < 4; ++r) {
        float v = acc2[r] + p2r[r];
        float vc = fminf(9.f, fmaxf(-9.f, v));
        float e = __expf(2.f * vc);
        float hh = (e - 1.f) * __builtin_amdgcn_rcpf(e + 1.f);
        const int row = rq * 4 + r;
        float ho = Hl[row * 33 + lch];
        float z = zreg[r];
        float hn = ho * (1.f - z) + z * hh;
        Hl[row * 33 + lch] = hn;
        u32 hb = (u32)__builtin_bit_cast(u16, (f16)hn);
        gwrite(h16, g * 16 + row, ci2, hb);
        if (t == 511) out[(size_t)(g * 16 + row) * 512 + ci2] = hn;
      }
    }
    if (t < 511) ab = barK(2u * t + 3u, false);
  }
}

// ---------------- launch ---------------------------------------------------
extern "C" void kernel_launch(void* const* d_in, const int* in_sizes, int n_in,
                              void* d_out, int out_size, void* d_ws, size_t ws_size,
                              hipStream_t stream) {
  const float* x  = (const float*)d_in[0];
  const float* h0 = (const float*)d_in[1];
  const float* wr = (const float*)d_in[2];
  const float* wz = (const float*)d_in[3];
  const float* wh = (const float*)d_in[4];
  const float* br = (const float*)d_in[5];
  const float* bz = (const float*)d_in[6];
  const float* bh = (const float*)d_in[7];
  float* out = (float*)d_out;

  char* ws = (char*)d_ws;
  size_t off = 0;
  f16* WT = (f16*)(ws + off);   off += (size_t)1536 * 1024 * 2;        // 3 MiB
  f16* pre = (f16*)(ws + off);  off += (size_t)512 * 64 * 1536 * 2;    // 96 MiB
  f16* h16 = (f16*)(ws + off);  off += (size_t)64 * 512 * 2;
  f16* hr16 = (f16*)(ws + off); off += (size_t)64 * 512 * 2;
  u32* syncb = (u32*)(ws + off); off += 32768;

  if (ws_size < off) {
    hipMemsetAsync(d_out, 0, (size_t)out_size * 4, stream);
    return;
  }

  hipMemsetAsync(syncb, 0, 32768, stream);
  probe_xcd_k<<<512, 64, 0, stream>>>(syncb);
  cvt_weights_k<<<dim3(1024, 3), 512, 0, stream>>>(wr, wz, wh, WT);
  precompute_x_k<<<dim3(512, 6), 256, 0, stream>>>(x, WT, br, bz, bh, pre);
  hipFuncSetAttribute(reinterpret_cast<const void*>(gru_rec_k),
                      hipFuncAttributeMaxDynamicSharedMemorySize, LDS_REC);
  gru_rec_k<<<1024, 256, LDS_REC, stream>>>(WT, pre, h0, h16, hr16, syncb, out);
}